// Round 3
// baseline (200.300 us; speedup 1.0000x reference)
//
#include <hip/hip_runtime.h>
#include <hip/hip_bf16.h>
#include <stdint.h>

// NTXentLoss: B=4096, D=512, N=8192, tau=0.07, out = scalar mean loss.
// loss_i = -sim[i, i^B] + M + log( sum_{j != i} exp(sim_ij - M) ),  M = 1/tau
//
// R5: counted-lgkm fragment pipeline. R4's phases drained lgkmcnt(0) right
// before each MFMA cluster with 4 barriers/K-tile -> ~1575 cyc/phase (vs
// m201's 344 at identical per-phase work). Now each phase issues the NEXT
// phase's ds_reads and waits lgkmcnt(4/8) (never 0) on reads issued a full
// phase earlier; staging is depth-3 (stage T+3 during T, vmcnt(4) confirms
// T+2 at tile end); ONE barrier per K-tile. Fragments ping-pong between
// static register sets (afX/afY/bfX/bfY + afH). kfinal fused into ksim via
// last-block pattern (threadfence + done counter). 2 launches total.

#define N_TOT   8192
#define B_HALF  4096
#define DDIM    512
#define INV_TAU 14.285714285714286f   // 1/0.07 == fixed logsumexp offset M
#define TTILES  32                    // 8192 / 256
#define NKT     16                    // 512 / 32

typedef __bf16 bf16x8 __attribute__((ext_vector_type(8)));
typedef __bf16 bf16x4 __attribute__((ext_vector_type(4)));
typedef float  floatx4 __attribute__((ext_vector_type(4)));

__device__ __forceinline__ void gl2lds16(const void* g, void* l) {
    __builtin_amdgcn_global_load_lds(
        (const __attribute__((address_space(1))) void*)g,
        (__attribute__((address_space(3))) void*)l, 16, 0, 0);
}

#define S_BARRIER() asm volatile("s_barrier" ::: "memory")
#define VMCNT4()    asm volatile("s_waitcnt vmcnt(4)" ::: "memory")
#define VMCNT0()    asm volatile("s_waitcnt vmcnt(0)" ::: "memory")
#define VM_NONE()   do {} while (0)

// ---------------- kernel 1: normalize rows, fp32 -> bf16 z; zero sums/ctr ---
__global__ __launch_bounds__(256) void knorm(const float* __restrict__ anchor,
                                             const float* __restrict__ positive,
                                             __bf16* __restrict__ z,
                                             float* __restrict__ row_sums,
                                             unsigned* __restrict__ done_ctr) {
    const int row  = blockIdx.x * 4 + (threadIdx.x >> 6);
    const int lane = threadIdx.x & 63;
    if (lane == 0) row_sums[row] = 0.0f;   // replaces hipMemsetAsync
    if (blockIdx.x == 0 && threadIdx.x == 0) *done_ctr = 0u;
    const float* src = (row < B_HALF) ? (anchor + (size_t)row * DDIM)
                                      : (positive + (size_t)(row - B_HALF) * DDIM);
    float4 v0 = ((const float4*)src)[lane];
    float4 v1 = ((const float4*)src)[lane + 64];
    float ss = v0.x*v0.x + v0.y*v0.y + v0.z*v0.z + v0.w*v0.w
             + v1.x*v1.x + v1.y*v1.y + v1.z*v1.z + v1.w*v1.w;
    #pragma unroll
    for (int m = 1; m < 64; m <<= 1) ss += __shfl_xor(ss, m, 64);
    const float inv = 1.0f / fmaxf(sqrtf(ss), 1e-8f);
    bf16x4 o0, o1;
    o0[0] = (__bf16)(v0.x*inv); o0[1] = (__bf16)(v0.y*inv);
    o0[2] = (__bf16)(v0.z*inv); o0[3] = (__bf16)(v0.w*inv);
    o1[0] = (__bf16)(v1.x*inv); o1[1] = (__bf16)(v1.y*inv);
    o1[2] = (__bf16)(v1.z*inv); o1[3] = (__bf16)(v1.w*inv);
    bf16x4* dst = (bf16x4*)(z + (size_t)row * DDIM);
    dst[lane]      = o0;
    dst[lane + 64] = o1;
}

// ---------------- kernel 2: upper-triangle 256x256 sim tiles, fused exp-sum --
// Grid 528 = 32*33/2 tile-pairs (rt <= ct). 512 threads = 8 waves (2M x 4N).
// Per wave: 128x64 of C as acc[8][4] 16x16x32 fragments. LDS: 4 K-slots of
// (A 256x32 + B 256x32) bf16 = 4 x 32 KiB. Depth-3 staging, counted vmcnt,
// counted-lgkm fragment prefetch, 1 barrier per K-tile. Last block computes
// the final loss (fused kfinal).
__global__ __launch_bounds__(512, 2) void ksim(const __bf16* __restrict__ z,
                                               float* __restrict__ row_sums,
                                               float* __restrict__ pos_sims,
                                               unsigned* __restrict__ done_ctr,
                                               float* __restrict__ out) {
    // XCD-chunked bijective swizzle (528 = 8 * 66), then triangular decode.
    int bid = (int)blockIdx.x;
    bid = (bid & 7) * 66 + (bid >> 3);
    int rem = bid, rt = 0;
    while (rem >= TTILES - rt) { rem -= TTILES - rt; rt++; }
    const int ct = rt + rem;
    const bool diag = (rt == ct);
    const bool posb = (ct == rt + 16);   // pos pair (i, i+4096) lives here

    const int r0 = rt * 256, c0 = ct * 256;
    const int tid  = threadIdx.x;
    const int w    = tid >> 6, lane = tid & 63;
    const int quad = lane >> 4, nlo = lane & 15;
    const int wr   = w >> 2,   wc  = w & 3;
    const int s4   = (nlo >> 1) & 3;     // read-side chunk swizzle (lane-const)

    __shared__ __align__(16) char smem[4][32768];   // slot = [A 16K][B 16K]
    __shared__ unsigned lastf;
    __shared__ float fsum[8];

    // staging: wave-instruction covers 16 rows x 64 B; LDS dest is linear
    // (wave-uniform base + lane*16); chunk permutation applied on the GLOBAL
    // source address: lane L holds (row = base + L>>2, chunk = (L&3)^((L>>3)&3)).
    const int schunk = ((lane & 3) ^ ((lane >> 3) & 3)) * 8;
    const __bf16* zA = z + (size_t)(r0 + w * 16 + (lane >> 2)) * DDIM + schunk;
    const __bf16* zB = z + (size_t)(c0 + w * 16 + (lane >> 2)) * DDIM + schunk;

#define STAGE_A(T2) do { char* s_ = smem[(T2) & 3]; const int kb_ = (T2) * 32;   \
        gl2lds16(zA + kb_,              s_ + w * 1024);                          \
        gl2lds16(zA + 128 * DDIM + kb_, s_ + 8192 + w * 1024); } while (0)
#define STAGE_B(T2) do { char* s_ = smem[(T2) & 3]; const int kb_ = (T2) * 32;   \
        gl2lds16(zB + kb_,              s_ + 16384 + w * 1024);                  \
        gl2lds16(zB + 128 * DDIM + kb_, s_ + 16384 + 8192 + w * 1024); } while (0)

    floatx4 acc[8][4];
    #pragma unroll
    for (int a = 0; a < 8; a++)
        #pragma unroll
        for (int b = 0; b < 4; b++) acc[a][b] = (floatx4){0.f, 0.f, 0.f, 0.f};

    // fragment register sets (static names only -- rule #20)
    bf16x8 afX[4], afY[4], afH[4], bfX[4], bfY[4];
    const char* smb = (const char*)smem;
    const int xo   = (quad ^ s4) * 16;
    const int aoff = (wr * 128 + nlo) * 64 + xo;            // lo-A frag base
    const int boff = 16384 + (wc * 64 + nlo) * 64 + xo;     // B frag base

    // prologue: stage tiles 0..2 (12 loads/wave); vmcnt(4) => tiles 0,1
    // resident (tile 2's 4 loads stay in flight = steady-state invariant).
    STAGE_A(0); STAGE_B(0);
    STAGE_A(1); STAGE_B(1);
    STAGE_A(2); STAGE_B(2);
    VMCNT4();
    S_BARRIER();
    // issue R0: lo-A(0) + B(0)  [8 ds_reads outstanding entering TILE(0)]
    #pragma unroll
    for (int mi = 0; mi < 4; mi++)
        afX[mi] = *(const bf16x8*)(smb + aoff + mi * 1024);
    #pragma unroll
    for (int ni = 0; ni < 4; ni++)
        bfX[ni] = *(const bf16x8*)(smb + boff + ni * 1024);

    // Per tile T: ph0 issues hi-A(T) [4 ds], waits lgkm(4) (covers prior
    // lo-A+B), MFMA acc[0..3]; ph1 issues lo-A(T+1)+B(T+1) [8 ds], waits
    // lgkm(8) (covers hi-A), MFMA acc[4..7]; vmcnt; ONE barrier.
#define TILE(T, AC, AN, BC, BN, DO_STAGE, ISSUE_NEXT, VMW) do {                        \
        const int sl_ = ((T) & 3) * 32768, sn_ = (((T) + 1) & 3) * 32768;              \
        _Pragma("unroll") for (int mi = 0; mi < 4; mi++)                               \
            afH[mi] = *(const bf16x8*)(smb + sl_ + aoff + 4096 + mi * 1024);           \
        if (DO_STAGE) { STAGE_A((T) + 3); }                                            \
        asm volatile("s_waitcnt lgkmcnt(4)" ::: "memory");                             \
        __builtin_amdgcn_sched_barrier(0);                                             \
        __builtin_amdgcn_s_setprio(1);                                                 \
        _Pragma("unroll") for (int mi = 0; mi < 4; mi++)                               \
            _Pragma("unroll") for (int ni = 0; ni < 4; ni++)                           \
                acc[mi][ni] = __builtin_amdgcn_mfma_f32_16x16x32_bf16(                 \
                    AC[mi], BC[ni], acc[mi][ni], 0, 0, 0);                             \
        __builtin_amdgcn_s_setprio(0);                                                 \
        if (ISSUE_NEXT) {                                                              \
            _Pragma("unroll") for (int mi = 0; mi < 4; mi++)                           \
                AN[mi] = *(const bf16x8*)(smb + sn_ + aoff + mi * 1024);               \
            _Pragma("unroll") for (int ni = 0; ni < 4; ni++)                           \
                BN[ni] = *(const bf16x8*)(smb + sn_ + boff + ni * 1024);               \
        }                                                                              \
        if (DO_STAGE) { STAGE_B((T) + 3); }                                            \
        if (ISSUE_NEXT) { asm volatile("s_waitcnt lgkmcnt(8)" ::: "memory"); }         \
        else            { asm volatile("s_waitcnt lgkmcnt(0)" ::: "memory"); }         \
        __builtin_amdgcn_sched_barrier(0);                                             \
        __builtin_amdgcn_s_setprio(1);                                                 \
        _Pragma("unroll") for (int mi = 0; mi < 4; mi++)                               \
            _Pragma("unroll") for (int ni = 0; ni < 4; ni++)                           \
                acc[4 + mi][ni] = __builtin_amdgcn_mfma_f32_16x16x32_bf16(             \
                    afH[mi], BC[ni], acc[4 + mi][ni], 0, 0, 0);                        \
        __builtin_amdgcn_s_setprio(0);                                                 \
        VMW();                                                                         \
        S_BARRIER();                                                                   \
    } while (0)

    TILE( 0, afX, afY, bfX, bfY, 1, 1, VMCNT4);
    TILE( 1, afY, afX, bfY, bfX, 1, 1, VMCNT4);
    TILE( 2, afX, afY, bfX, bfY, 1, 1, VMCNT4);
    TILE( 3, afY, afX, bfY, bfX, 1, 1, VMCNT4);
    TILE( 4, afX, afY, bfX, bfY, 1, 1, VMCNT4);
    TILE( 5, afY, afX, bfY, bfX, 1, 1, VMCNT4);
    TILE( 6, afX, afY, bfX, bfY, 1, 1, VMCNT4);
    TILE( 7, afY, afX, bfY, bfX, 1, 1, VMCNT4);
    TILE( 8, afX, afY, bfX, bfY, 1, 1, VMCNT4);
    TILE( 9, afY, afX, bfY, bfX, 1, 1, VMCNT4);
    TILE(10, afX, afY, bfX, bfY, 1, 1, VMCNT4);
    TILE(11, afY, afX, bfY, bfX, 1, 1, VMCNT4);
    TILE(12, afX, afY, bfX, bfY, 1, 1, VMCNT4);   // stages tile 15
    TILE(13, afY, afX, bfY, bfX, 0, 1, VMCNT0);   // confirms tile 15
    TILE(14, afX, afY, bfX, bfY, 0, 1, VM_NONE);
    TILE(15, afY, afX, bfY, bfX, 0, 0, VM_NONE);

    // ---------------- epilogue: exp, exclusions, LDS partial-reduce ----------
    __syncthreads();                       // all slot reads done; smem reusable
    float* rbuf = (float*)smem;            // [256][4] : row partial per wc-wave
    float* cbuf = (float*)(smem[0] + 4096);// [256][2] : col partial per wr-wave

    float cs[4] = {0.f, 0.f, 0.f, 0.f};
    #pragma unroll
    for (int mi = 0; mi < 8; mi++) {
        #pragma unroll
        for (int reg = 0; reg < 4; reg++) {
            const int il = wr * 128 + mi * 16 + quad * 4 + reg;  // local row
            const int i  = r0 + il;
            const int ipos = i ^ B_HALF;
            float rs = 0.f;
            #pragma unroll
            for (int ni = 0; ni < 4; ni++) {
                const int j = c0 + wc * 64 + ni * 16 + nlo;
                const float sim = acc[mi][ni][reg] * INV_TAU;
                float e = __expf(sim - INV_TAU);
                if (diag && j == i) e = 0.f;          // exclude self
                if (posb && j == ipos) {              // unique writer per pair
                    pos_sims[i] = sim;
                    pos_sims[j] = sim;
                }
                rs += e;
                cs[ni] += e;
            }
            rs += __shfl_xor(rs, 1, 64);
            rs += __shfl_xor(rs, 2, 64);
            rs += __shfl_xor(rs, 4, 64);
            rs += __shfl_xor(rs, 8, 64);
            if (nlo == 0) rbuf[il * 4 + wc] = rs;
        }
    }
    if (!diag) {   // symmetric contribution to column rows (off-diag only)
        #pragma unroll
        for (int ni = 0; ni < 4; ni++) {
            float c = cs[ni];
            c += __shfl_xor(c, 16, 64);
            c += __shfl_xor(c, 32, 64);
            if (quad == 0) cbuf[(wc * 64 + ni * 16 + nlo) * 2 + wr] = c;
        }
    }
    __syncthreads();
    if (tid < 256) {
        const float s = rbuf[tid * 4] + rbuf[tid * 4 + 1]
                      + rbuf[tid * 4 + 2] + rbuf[tid * 4 + 3];
        atomicAdd(&row_sums[r0 + tid], s);
    } else if (!diag) {
        const int c = tid - 256;
        atomicAdd(&row_sums[c0 + c], cbuf[c * 2] + cbuf[c * 2 + 1]);
    }

    // ---------------- fused kfinal: last block reduces the loss --------------
    __threadfence();                       // make this block's writes visible
    __syncthreads();
    if (tid == 0) lastf = (atomicAdd(done_ctr, 1u) == 527u) ? 1u : 0u;
    __syncthreads();
    if (!lastf) return;
    __threadfence();                       // acquire: all 528 blocks' writes
    float a = 0.f;
    for (int i = tid; i < N_TOT; i += 512)
        a += INV_TAU + __logf(row_sums[i]) - pos_sims[i];
    #pragma unroll
    for (int m = 1; m < 64; m <<= 1) a += __shfl_xor(a, m, 64);
    if (lane == 0) fsum[w] = a;
    __syncthreads();
    if (tid == 0) {
        float t = fsum[0] + fsum[1] + fsum[2] + fsum[3]
                + fsum[4] + fsum[5] + fsum[6] + fsum[7];
        out[0] = t * (1.0f / (float)N_TOT);
    }
#undef TILE
#undef STAGE_A
#undef STAGE_B
}

extern "C" void kernel_launch(void* const* d_in, const int* in_sizes, int n_in,
                              void* d_out, int out_size, void* d_ws, size_t ws_size,
                              hipStream_t stream) {
    const float* anchor   = (const float*)d_in[0];
    const float* positive = (const float*)d_in[1];
    float* out = (float*)d_out;

    char* ws = (char*)d_ws;
    __bf16* z        = (__bf16*)ws;                        // 8192*512*2 = 8 MB
    float*  row_sums = (float*)(ws + 8388608);             // 32 KB
    float*  pos_sims = (float*)(ws + 8388608 + 32768);     // 32 KB
    unsigned* done_ctr = (unsigned*)(ws + 8388608 + 65536);

    knorm<<<N_TOT / 4, 256, 0, stream>>>(anchor, positive, z, row_sums, done_ctr);
    ksim<<<528, 512, 0, stream>>>(z, row_sums, pos_sims, done_ctr, out);
}